// Round 5
// baseline (921.898 us; speedup 1.0000x reference)
//
#include <hip/hip_runtime.h>

// ---------------------------------------------------------------------------
// SingleHeadQKV: X@{Wq,Wk,Wv} -> rope+silu -> decay-masked QK^T -> @V -> GN
// B=2, T=4096, C=1024. GEMMs: 128x128 (av: 64x128) tile, BK=64,
// PIPELINED staging: buffer_load dwordx4 -> VGPR -> ds_write_b128 (swizzled).
// K-loop: ds_write(k) ; barrier ; issue loads(k+1) ; ds_read+MFMA(k) ; barrier
//   -> global loads of k+1 are in flight during the whole MFMA phase of k
//      (their vmcnt wait is at the NEXT iteration's ds_write).
// LDS chunk-XOR swizzle (phys chunk = logical ^ (row&7)) gives conflict-free
// b128 reads AND writes while global addresses stay perfectly lane-linear.
//
// ws layout (shorts):
//   Qb  [8192][1024]            @ 0        (16 MB)
//   Kb  [8192][1024]            @ 8M       (16 MB)
//   Vt  [1024][8192] transposed @ 16M      (16 MB)
//   Ab  [2*4096][4096]          @ 24M      (64 MB)   } aliased:
//   Xb  [8192][1024]            @ 24M      (16 MB)   } Xb/WT dead before
//   WT  [3072][1024]            @ 32M      ( 6 MB)   } score writes Ab
// ---------------------------------------------------------------------------

typedef __attribute__((ext_vector_type(8))) short bf16x8;
typedef __attribute__((ext_vector_type(4))) short bf16x4;
typedef __attribute__((ext_vector_type(4))) float f32x4;

#define MFMA16(a, b, c) __builtin_amdgcn_mfma_f32_16x16x32_bf16(a, b, c, 0, 0, 0)

static __device__ __forceinline__ short f2bf(float f) {
  unsigned u = __builtin_bit_cast(unsigned, f);
  u = (u + 0x7fffu + ((u >> 16) & 1u)) >> 16;
  return (short)u;
}

#define T_LEN 4096
#define CIN 1024

// log2(0.99609375)
#define LOG2G (-0.0056465633f)
// log2(10000)/32
#define L2IF (0.41524101f)

// ---------------------------------------------------------------------------
// Kernel A: X fp32 -> bf16 row-major copy.
// ---------------------------------------------------------------------------
__global__ __launch_bounds__(256)
void convert_x(const float* __restrict__ X, short* __restrict__ Xb) {
  const size_t id = (size_t)blockIdx.x * 256 + threadIdx.x;
  float4 f = *(const float4*)&X[id * 4];
  bf16x4 v = {f2bf(f.x), f2bf(f.y), f2bf(f.z), f2bf(f.w)};
  *(bf16x4*)&Xb[id * 4] = v;
}

// ---------------------------------------------------------------------------
// Kernel B: WT[c][k] = W_mat[k][c%1024], bf16. 64x64 LDS tile transpose.
// ---------------------------------------------------------------------------
__global__ __launch_bounds__(256)
void transpose_w(const float* __restrict__ Wq, const float* __restrict__ Wk,
                 const float* __restrict__ Wv, short* __restrict__ WT) {
  const int k0 = blockIdx.x * 64, n0 = blockIdx.y * 64, mat = blockIdx.z;
  const float* __restrict__ W = (mat == 0) ? Wq : (mat == 1) ? Wk : Wv;
  __shared__ short tile[64][72];
  const int tid = threadIdx.x;
  const int r = tid >> 4, c = tid & 15;
#pragma unroll
  for (int i = 0; i < 4; ++i) {
    int row = r + 16 * i;
    float4 f = *(const float4*)&W[(size_t)(k0 + row) * CIN + n0 + c * 4];
    tile[c * 4 + 0][row] = f2bf(f.x);
    tile[c * 4 + 1][row] = f2bf(f.y);
    tile[c * 4 + 2][row] = f2bf(f.z);
    tile[c * 4 + 3][row] = f2bf(f.w);
  }
  __syncthreads();
  const int n = tid >> 2, seg = tid & 3;
  bf16x8 lo = *(const bf16x8*)&tile[n][seg * 16];
  bf16x8 hi = *(const bf16x8*)&tile[n][seg * 16 + 8];
  short* dst = &WT[(size_t)(mat * 1024 + n0 + n) * CIN + k0 + seg * 16];
  *(bf16x8*)dst = lo;
  *(bf16x8*)(dst + 8) = hi;
}

// ---------------------------------------------------------------------------
// Shared tile-GEMM machinery: BK=64, LDS [rows][64] shorts, chunk-XOR swizzle.
// Staging: thread t owns rows i*32+(t>>3), logical chunk t&7 (16B).
//   global: lane-linear dwordx4 (wave = 8 rows x 128B contiguous).
//   LDS phys chunk = (t&7) ^ (row&7)  -> writes hit 8 distinct chunks per
//   8-lane group (conflict-free); frag reads XOR the same way.
// ---------------------------------------------------------------------------
#define GEMM_DECLS()                                   \
  const int tid = threadIdx.x;                         \
  const int lane = tid & 63, wave = tid >> 6;          \
  const int wm = wave >> 1, wn = wave & 1;             \
  const int l15 = lane & 15, quad = lane >> 4;         \
  const int srow = tid >> 3;                           \
  const int schunk = tid & 7;                          \
  const int swz = schunk ^ (srow & 7);                 \
  const int asw = (l15 & 7);

#define ACC_INIT4(acc)                                 \
  _Pragma("unroll") for (int i = 0; i < 4; ++i)        \
  _Pragma("unroll") for (int j = 0; j < 4; ++j) {      \
    f32x4 z = {0.f, 0.f, 0.f, 0.f};                    \
    acc[i][j] = z;                                     \
  }

// global -> regs (nrows/32 x dwordx4 per thread), lane-linear addresses
#define LOAD_TILE(reg, src, ld, r0, k0, nrows)                          \
  _Pragma("unroll") for (int i = 0; i < (nrows) / 32; ++i)              \
    reg[i] = *(const uint4*)&src[(size_t)((r0) + i * 32 + srow) * (ld) + \
                                 (k0) + schunk * 8];

// regs -> LDS, swizzled chunk
#define WRITE_TILE(dst, reg, nrows)                                     \
  _Pragma("unroll") for (int i = 0; i < (nrows) / 32; ++i)              \
    *(uint4*)&dst[i * 32 + srow][swz * 8] = reg[i];

#define FRAG_MFMA44(As, Bs, acc)                                            \
  {                                                                         \
    bf16x8 af[4][2], bfr[4][2];                                             \
    _Pragma("unroll") for (int im = 0; im < 4; ++im)                        \
    _Pragma("unroll") for (int ks = 0; ks < 2; ++ks)                        \
      af[im][ks] = *(const bf16x8*)&As[wm * 64 + im * 16 + l15]             \
                       [((ks * 4 + quad) ^ asw) * 8];                       \
    _Pragma("unroll") for (int in = 0; in < 4; ++in)                        \
    _Pragma("unroll") for (int ks = 0; ks < 2; ++ks)                        \
      bfr[in][ks] = *(const bf16x8*)&Bs[wn * 64 + in * 16 + l15]            \
                        [((ks * 4 + quad) ^ asw) * 8];                      \
    _Pragma("unroll") for (int ks = 0; ks < 2; ++ks)                        \
    _Pragma("unroll") for (int im = 0; im < 4; ++im)                        \
    _Pragma("unroll") for (int in = 0; in < 4; ++in)                        \
      acc[im][in] = MFMA16(af[im][ks], bfr[in][ks], acc[im][in]);           \
  }

// ---------------------------------------------------------------------------
// Kernel C: QKV GEMM. C[m][c] = sum_k Xb[m][k] WT[c][k].  M=8192, N=3072.
// grid (64 m-tiles, 24 c-tiles). Epilogue: rope(Q,K cols<64) + silu.
// ---------------------------------------------------------------------------
__global__ __launch_bounds__(256, 2)
void qkv_gemm(const short* __restrict__ Xb, const short* __restrict__ WT,
              short* __restrict__ Qb, short* __restrict__ Kb,
              short* __restrict__ Vt) {
  __shared__ __align__(16) short As[128][64];
  __shared__ __align__(16) short Bs[128][64];
  GEMM_DECLS();
  const int m0 = blockIdx.x * 128;
  const int c0 = blockIdx.y * 128;

  f32x4 acc[4][4];
  ACC_INIT4(acc);

  uint4 ra[4], rb[4];
  LOAD_TILE(ra, Xb, CIN, m0, 0, 128);
  LOAD_TILE(rb, WT, CIN, c0, 0, 128);

  for (int k0 = 0; k0 < CIN; k0 += 64) {
    WRITE_TILE(As, ra, 128);
    WRITE_TILE(Bs, rb, 128);
    __syncthreads();
    if (k0 + 64 < CIN) {
      LOAD_TILE(ra, Xb, CIN, m0, k0 + 64, 128);
      LOAD_TILE(rb, WT, CIN, c0, k0 + 64, 128);
    }
    FRAG_MFMA44(As, Bs, acc);
    __syncthreads();
  }

  const int mat = (c0 >> 10);  // block-uniform: 0=Q 1=K 2=V
#pragma unroll
  for (int im = 0; im < 4; ++im) {
#pragma unroll
    for (int in = 0; in < 4; ++in) {
      const int c = c0 + wn * 64 + in * 16 + l15;
      const int colm = c & 1023;
      const bool rope = (mat < 2) && (colm < 64);
      const float invf = exp2f(-L2IF * (float)(colm >> 1));
      const int mbase = m0 + wm * 64 + im * 16 + quad * 4;
      short vv[4];
#pragma unroll
      for (int r = 0; r < 4; ++r) {
        float v = acc[im][in][r];
        int m = mbase + r;
        int t = m & (T_LEN - 1);
        float partner = __shfl_xor(v, 1, 64);
        if (rope) {
          float ang = (float)t * invf;
          float s_, c_;
          sincosf(ang, &s_, &c_);
          v = (colm & 1) ? (v * c_ + partner * s_) : (v * c_ - partner * s_);
        }
        v = v / (1.f + __expf(-v));  // silu
        vv[r] = f2bf(v);
      }
      if (mat == 0) {
#pragma unroll
        for (int r = 0; r < 4; ++r) Qb[(size_t)(mbase + r) * 1024 + colm] = vv[r];
      } else if (mat == 1) {
#pragma unroll
        for (int r = 0; r < 4; ++r) Kb[(size_t)(mbase + r) * 1024 + colm] = vv[r];
      } else {
        bf16x4 v4 = {vv[0], vv[1], vv[2], vv[3]};
        *(bf16x4*)&Vt[(size_t)colm * 8192 + mbase] = v4;  // transposed
      }
    }
  }
}

// ---------------------------------------------------------------------------
// Kernel D: A' = decay o (Q K^T), bf16. Triangular grid: 528 tiles (si>=ti)
// per batch, grid (528, 2). Uniform work per block.
// ---------------------------------------------------------------------------
__global__ __launch_bounds__(256, 2)
void score_kernel(const short* __restrict__ Qb, const short* __restrict__ Kb,
                  short* __restrict__ Ab) {
  int idx = blockIdx.x;
  int ti = 0;
  while (idx >= 32 - ti) { idx -= 32 - ti; ++ti; }
  const int si = ti + idx;
  const int b = blockIdx.y;
  const int s0 = si * 128, t0 = ti * 128;

  __shared__ __align__(16) short Qs[128][64];
  __shared__ __align__(16) short Ks[128][64];
  GEMM_DECLS();

  f32x4 acc[4][4];
  ACC_INIT4(acc);

  uint4 ra[4], rb[4];
  LOAD_TILE(ra, Qb, 1024, b * T_LEN + t0, 0, 128);
  LOAD_TILE(rb, Kb, 1024, b * T_LEN + s0, 0, 128);

  for (int k0 = 0; k0 < 1024; k0 += 64) {
    WRITE_TILE(Qs, ra, 128);
    WRITE_TILE(Ks, rb, 128);
    __syncthreads();
    if (k0 + 64 < 1024) {
      LOAD_TILE(ra, Qb, 1024, b * T_LEN + t0, k0 + 64, 128);
      LOAD_TILE(rb, Kb, 1024, b * T_LEN + s0, k0 + 64, 128);
    }
    FRAG_MFMA44(Qs, Ks, acc);
    __syncthreads();
  }

#pragma unroll
  for (int im = 0; im < 4; ++im) {
#pragma unroll
    for (int in = 0; in < 4; ++in) {
      int s = s0 + wn * 64 + in * 16 + l15;
#pragma unroll
      for (int r = 0; r < 4; ++r) {
        int t = t0 + wm * 64 + im * 16 + quad * 4 + r;
        int d = s - t;
        float v = acc[im][in][r];
        v = (d < 0) ? 0.f : v * exp2f((float)d * LOG2G);
        Ab[((size_t)(b * T_LEN + t)) * T_LEN + s] = f2bf(v);
      }
    }
  }
}

// ---------------------------------------------------------------------------
// Kernel E: out = A' V (fp32). 64-row t-tiles, balanced pairing (p, 63-p):
// uniform 65 BK64-iters per block. grid (32, 2, 8) = 512 blocks.
// di slowest: A-stream-sharing blocks land on one XCD.
// ---------------------------------------------------------------------------
__global__ __launch_bounds__(256, 2)
void av_kernel(const short* __restrict__ Ab, const short* __restrict__ Vt,
               float* __restrict__ Out) {
  const int p = blockIdx.x, b = blockIdx.y, di = blockIdx.z;
  const int n0 = di * 128;

  __shared__ __align__(16) short As2[64][64];
  __shared__ __align__(16) short Vs[128][64];
  GEMM_DECLS();

#pragma unroll 1
  for (int half = 0; half < 2; ++half) {
    const int ti2 = half ? (63 - p) : p;  // 64-row tile index
    const int t0 = ti2 * 64;

    f32x4 acc[2][4];
#pragma unroll
    for (int i = 0; i < 2; ++i)
#pragma unroll
      for (int j = 0; j < 4; ++j) {
        f32x4 z = {0.f, 0.f, 0.f, 0.f};
        acc[i][j] = z;
      }

    uint4 ra[2], rb[4];
    LOAD_TILE(ra, Ab, T_LEN, b * T_LEN + t0, t0, 64);
    LOAD_TILE(rb, Vt, 8192, n0, b * T_LEN + t0, 128);

    for (int s = t0; s < T_LEN; s += 64) {
      WRITE_TILE(As2, ra, 64);
      WRITE_TILE(Vs, rb, 128);
      __syncthreads();
      if (s + 64 < T_LEN) {
        LOAD_TILE(ra, Ab, T_LEN, b * T_LEN + t0, s + 64, 64);
        LOAD_TILE(rb, Vt, 8192, n0, b * T_LEN + s + 64, 128);
      }
      bf16x8 af[2][2], bfr[4][2];
#pragma unroll
      for (int im = 0; im < 2; ++im)
#pragma unroll
        for (int ks = 0; ks < 2; ++ks)
          af[im][ks] = *(const bf16x8*)&As2[wm * 32 + im * 16 + l15]
                           [((ks * 4 + quad) ^ asw) * 8];
#pragma unroll
      for (int in = 0; in < 4; ++in)
#pragma unroll
        for (int ks = 0; ks < 2; ++ks)
          bfr[in][ks] = *(const bf16x8*)&Vs[wn * 64 + in * 16 + l15]
                            [((ks * 4 + quad) ^ asw) * 8];
#pragma unroll
      for (int ks = 0; ks < 2; ++ks)
#pragma unroll
        for (int im = 0; im < 2; ++im)
#pragma unroll
          for (int in = 0; in < 4; ++in)
            acc[im][in] = MFMA16(af[im][ks], bfr[in][ks], acc[im][in]);
      __syncthreads();
    }

#pragma unroll
    for (int im = 0; im < 2; ++im) {
#pragma unroll
      for (int in = 0; in < 4; ++in) {
        int n = n0 + wn * 64 + in * 16 + l15;
#pragma unroll
        for (int r = 0; r < 4; ++r) {
          int t = t0 + wm * 32 + im * 16 + quad * 4 + r;
          Out[((size_t)(b * T_LEN + t)) * 1024 + n] = acc[im][in][r];
        }
      }
    }
  }
}

// ---------------------------------------------------------------------------
// Kernel F: in-place GroupNorm (32 groups x 32 ch). one block per row.
// ---------------------------------------------------------------------------
__global__ __launch_bounds__(256)
void gn_kernel(float* __restrict__ Out, const float* __restrict__ gw,
               const float* __restrict__ gb) {
  const int row = blockIdx.x;
  const int tid = threadIdx.x;
  const int ch0 = tid * 4;
  float4 v = *(const float4*)&Out[(size_t)row * 1024 + ch0];
  float s = v.x + v.y + v.z + v.w;
  float q = v.x * v.x + v.y * v.y + v.z * v.z + v.w * v.w;
  s += __shfl_xor(s, 1, 64);
  q += __shfl_xor(q, 1, 64);
  s += __shfl_xor(s, 2, 64);
  q += __shfl_xor(q, 2, 64);
  s += __shfl_xor(s, 4, 64);
  q += __shfl_xor(q, 4, 64);
  float mean = s * (1.f / 32.f);
  float var = q * (1.f / 32.f) - mean * mean;
  float rstd = rsqrtf(var + 1e-6f);
  float4 o;
  o.x = (v.x - mean) * rstd * gw[ch0 + 0] + gb[ch0 + 0];
  o.y = (v.y - mean) * rstd * gw[ch0 + 1] + gb[ch0 + 1];
  o.z = (v.z - mean) * rstd * gw[ch0 + 2] + gb[ch0 + 2];
  o.w = (v.w - mean) * rstd * gw[ch0 + 3] + gb[ch0 + 3];
  *(float4*)&Out[(size_t)row * 1024 + ch0] = o;
}

// ---------------------------------------------------------------------------
extern "C" void kernel_launch(void* const* d_in, const int* in_sizes, int n_in,
                              void* d_out, int out_size, void* d_ws,
                              size_t ws_size, hipStream_t stream) {
  const float* X = (const float*)d_in[0];
  const float* Wq = (const float*)d_in[1];
  const float* Wk = (const float*)d_in[2];
  const float* Wv = (const float*)d_in[3];
  const float* gw = (const float*)d_in[4];
  const float* gb = (const float*)d_in[5];
  float* Out = (float*)d_out;

  short* Qb = (short*)d_ws;                        // 16 MB
  short* Kb = Qb + (size_t)8192 * 1024;            // 16 MB
  short* Vt = Kb + (size_t)8192 * 1024;            // 16 MB (transposed)
  short* Ab = Vt + (size_t)8192 * 1024;            // 64 MB
  short* Xb = Ab;                                  // aliases Ab (dead after qkv)
  short* WT = Xb + (size_t)8192 * 1024;            // 6 MB

  convert_x<<<8192, 256, 0, stream>>>(X, Xb);
  transpose_w<<<dim3(16, 16, 3), 256, 0, stream>>>(Wq, Wk, Wv, WT);
  qkv_gemm<<<dim3(64, 24), 256, 0, stream>>>(Xb, WT, Qb, Kb, Vt);
  score_kernel<<<dim3(528, 2), 256, 0, stream>>>(Qb, Kb, Ab);
  av_kernel<<<dim3(32, 2, 8), 256, 0, stream>>>(Ab, Vt, Out);
  gn_kernel<<<8192, 256, 0, stream>>>(Out, gw, gb);
}

// Round 6
// 318.503 us; speedup vs baseline: 2.8945x; 2.8945x over previous
//
#include <hip/hip_runtime.h>

// ---------------------------------------------------------------------------
// SingleHeadQKV: X@{Wq,Wk,Wv} -> rope+silu -> decay-masked QK^T -> @V -> GN
// B=2, T=4096, C=1024. GEMMs: 128x128 (av: 64x128) tile, BK=64,
// global_load_lds(16B) LINEAR staging, bf16 MFMA 16x16x32, fp32 accumulate.
//
// DATA-LAYOUT swizzle: every staged buffer stores element (row, col) with its
// 16B chunk XOR-permuted: phys_chunk = (col>>3) ^ (row&7) within each 128B
// group. Producers write swizzled; GEMM staging is perfectly linear
// global_load_lds (fast DMA path, no data VGPRs); fragment reads XOR the
// chunk index (validated in R4) -> conflict-free b128 LDS reads.
//
// ws layout (shorts):
//   Qb  [8192][1024]            @ 0        (16 MB)
//   Kb  [8192][1024]            @ 8M       (16 MB)
//   Vt  [1024][8192] transposed @ 16M      (16 MB)
//   Ab  [2*4096][4096]          @ 24M      (64 MB)   } aliased:
//   Xb  [8192][1024]            @ 24M      (16 MB)   } Xb/WT dead before
//   WT  [3072][1024]            @ 32M      ( 6 MB)   } score writes Ab
// ---------------------------------------------------------------------------

typedef __attribute__((ext_vector_type(8))) short bf16x8;
typedef __attribute__((ext_vector_type(4))) short bf16x4;
typedef __attribute__((ext_vector_type(4))) float f32x4;

#define MFMA16(a, b, c) __builtin_amdgcn_mfma_f32_16x16x32_bf16(a, b, c, 0, 0, 0)

static __device__ __forceinline__ short f2bf(float f) {
  unsigned u = __builtin_bit_cast(unsigned, f);
  u = (u + 0x7fffu + ((u >> 16) & 1u)) >> 16;
  return (short)u;
}

static __device__ __forceinline__ void gl_lds16(const void* g, void* l) {
  __builtin_amdgcn_global_load_lds(
      (const __attribute__((address_space(1))) void*)g,
      (__attribute__((address_space(3))) void*)l, 16, 0, 0);
}

// swizzled column offset for element (row, col) in a swizzled buffer
static __device__ __forceinline__ int swzc(int col, int row) {
  return (((col >> 3) ^ (row & 7)) << 3) | (col & 7);
}

#define T_LEN 4096
#define CIN 1024

// log2(0.99609375)
#define LOG2G (-0.0056465633f)
// log2(10000)/32
#define L2IF (0.41524101f)

// ---------------------------------------------------------------------------
// Kernel A: X fp32 -> bf16, swizzled chunks. One 16B chunk per thread.
// ---------------------------------------------------------------------------
__global__ __launch_bounds__(256)
void convert_x(const float* __restrict__ X, short* __restrict__ Xb) {
  const int gid = blockIdx.x * 256 + threadIdx.x;  // chunk id
  const int row = gid >> 7;                        // 128 chunks per 1024-row
  const int c = gid & 127;
  const float* s = &X[(size_t)gid * 8];
  float4 f0 = *(const float4*)s;
  float4 f1 = *(const float4*)(s + 4);
  bf16x8 v = {f2bf(f0.x), f2bf(f0.y), f2bf(f0.z), f2bf(f0.w),
              f2bf(f1.x), f2bf(f1.y), f2bf(f1.z), f2bf(f1.w)};
  const int pc = (c & 0x78) | ((c ^ row) & 7);
  *(bf16x8*)&Xb[(size_t)row * 1024 + pc * 8] = v;
}

// ---------------------------------------------------------------------------
// Kernel B: WT[c][k] = W_mat[k][c%1024], bf16, swizzled. 64x64 LDS transpose.
// ---------------------------------------------------------------------------
__global__ __launch_bounds__(256)
void transpose_w(const float* __restrict__ Wq, const float* __restrict__ Wk,
                 const float* __restrict__ Wv, short* __restrict__ WT) {
  const int k0 = blockIdx.x * 64, n0 = blockIdx.y * 64, mat = blockIdx.z;
  const float* __restrict__ W = (mat == 0) ? Wq : (mat == 1) ? Wk : Wv;
  __shared__ short tile[64][72];
  const int tid = threadIdx.x;
  const int r = tid >> 4, c = tid & 15;
#pragma unroll
  for (int i = 0; i < 4; ++i) {
    int row = r + 16 * i;
    float4 f = *(const float4*)&W[(size_t)(k0 + row) * CIN + n0 + c * 4];
    tile[c * 4 + 0][row] = f2bf(f.x);
    tile[c * 4 + 1][row] = f2bf(f.y);
    tile[c * 4 + 2][row] = f2bf(f.z);
    tile[c * 4 + 3][row] = f2bf(f.w);
  }
  __syncthreads();
  const int n = tid >> 2, seg = tid & 3;
  bf16x8 lo = *(const bf16x8*)&tile[n][seg * 16];
  bf16x8 hi = *(const bf16x8*)&tile[n][seg * 16 + 8];
  const int R = mat * 1024 + n0 + n;
  const int a0 = (k0 >> 3) + seg * 2;  // absolute chunk of first 16B
  short* base = &WT[(size_t)R * CIN];
  *(bf16x8*)&base[(a0 ^ (n & 7)) * 8] = lo;
  *(bf16x8*)&base[((a0 + 1) ^ (n & 7)) * 8] = hi;
}

// ---------------------------------------------------------------------------
// Shared tile-GEMM machinery: BK=64, LDS [rows][64] shorts.
// Staging: linear gl_lds16 (thread t: row t>>3, chunk t&7). Data in the
// buffers is pre-swizzled, so LDS phys chunk lc of row r holds logical chunk
// lc^(r&7); fragment reads XOR by (l15&7).
// ---------------------------------------------------------------------------
#define GEMM_DECLS()                                   \
  const int tid = threadIdx.x;                         \
  const int lane = tid & 63, wave = tid >> 6;          \
  const int wm = wave >> 1, wn = wave & 1;             \
  const int l15 = lane & 15, quad = lane >> 4;         \
  const int srow = tid >> 3;                           \
  const int scol = (tid & 7) * 8;                      \
  const int asw = (l15 & 7);

#define ACC_INIT4(acc)                                 \
  _Pragma("unroll") for (int i = 0; i < 4; ++i)        \
  _Pragma("unroll") for (int j = 0; j < 4; ++j) {      \
    f32x4 z = {0.f, 0.f, 0.f, 0.f};                    \
    acc[i][j] = z;                                     \
  }

#define STAGE_TILE(dst, src, ld, r0, k0, nrows)        \
  _Pragma("unroll") for (int i = 0; i < (nrows) / 32; ++i) \
    gl_lds16(&src[(size_t)((r0) + i * 32 + srow) * (ld) + (k0) + scol], \
             &dst[i * 32 + srow][scol]);

#define FRAG_MFMA44(As, Bs, acc)                                            \
  {                                                                         \
    bf16x8 af[4][2], bfr[4][2];                                             \
    _Pragma("unroll") for (int im = 0; im < 4; ++im)                        \
    _Pragma("unroll") for (int ks = 0; ks < 2; ++ks)                        \
      af[im][ks] = *(const bf16x8*)&As[wm * 64 + im * 16 + l15]             \
                       [((ks * 4 + quad) ^ asw) * 8];                       \
    _Pragma("unroll") for (int in = 0; in < 4; ++in)                        \
    _Pragma("unroll") for (int ks = 0; ks < 2; ++ks)                        \
      bfr[in][ks] = *(const bf16x8*)&Bs[wn * 64 + in * 16 + l15]            \
                        [((ks * 4 + quad) ^ asw) * 8];                      \
    _Pragma("unroll") for (int ks = 0; ks < 2; ++ks)                        \
    _Pragma("unroll") for (int im = 0; im < 4; ++im)                        \
    _Pragma("unroll") for (int in = 0; in < 4; ++in)                        \
      acc[im][in] = MFMA16(af[im][ks], bfr[in][ks], acc[im][in]);           \
  }

// ---------------------------------------------------------------------------
// Kernel C: QKV GEMM. C[m][c] = sum_k Xb[m][k] WT[c][k].  M=8192, N=3072.
// grid (64 m-tiles, 24 c-tiles). Epilogue: rope(Q,K cols<64) + silu.
// ---------------------------------------------------------------------------
__global__ __launch_bounds__(256, 2)
void qkv_gemm(const short* __restrict__ Xb, const short* __restrict__ WT,
              short* __restrict__ Qb, short* __restrict__ Kb,
              short* __restrict__ Vt) {
  __shared__ __align__(16) short As[128][64];
  __shared__ __align__(16) short Bs[128][64];
  GEMM_DECLS();
  const int m0 = blockIdx.x * 128;
  const int c0 = blockIdx.y * 128;

  f32x4 acc[4][4];
  ACC_INIT4(acc);

  for (int k0 = 0; k0 < CIN; k0 += 64) {
    __syncthreads();
    STAGE_TILE(As, Xb, CIN, m0, k0, 128);
    STAGE_TILE(Bs, WT, CIN, c0, k0, 128);
    __syncthreads();
    FRAG_MFMA44(As, Bs, acc);
  }

  const int mat = (c0 >> 10);  // block-uniform: 0=Q 1=K 2=V
#pragma unroll
  for (int im = 0; im < 4; ++im) {
#pragma unroll
    for (int in = 0; in < 4; ++in) {
      const int c = c0 + wn * 64 + in * 16 + l15;
      const int colm = c & 1023;
      const bool rope = (mat < 2) && (colm < 64);
      const float invf = exp2f(-L2IF * (float)(colm >> 1));
      const int mbase = m0 + wm * 64 + im * 16 + quad * 4;
      short vv[4];
#pragma unroll
      for (int r = 0; r < 4; ++r) {
        float v = acc[im][in][r];
        int m = mbase + r;
        int t = m & (T_LEN - 1);
        float partner = __shfl_xor(v, 1, 64);
        if (rope) {
          float ang = (float)t * invf;
          float s_, c_;
          sincosf(ang, &s_, &c_);
          v = (colm & 1) ? (v * c_ + partner * s_) : (v * c_ - partner * s_);
        }
        v = v / (1.f + __expf(-v));  // silu
        vv[r] = f2bf(v);
      }
      if (mat == 0) {
#pragma unroll
        for (int r = 0; r < 4; ++r)
          Qb[(size_t)(mbase + r) * 1024 + swzc(colm, mbase + r)] = vv[r];
      } else if (mat == 1) {
#pragma unroll
        for (int r = 0; r < 4; ++r)
          Kb[(size_t)(mbase + r) * 1024 + swzc(colm, mbase + r)] = vv[r];
      } else {
        // Vt[colm][mbase..+3], swizzled by row colm; 8B lies inside one chunk
        bf16x4 v4 = {vv[0], vv[1], vv[2], vv[3]};
        *(bf16x4*)&Vt[(size_t)colm * 8192 +
                      (((mbase >> 3) ^ (colm & 7)) << 3) + (mbase & 7)] = v4;
      }
    }
  }
}

// ---------------------------------------------------------------------------
// Kernel D: A' = decay o (Q K^T), bf16 swizzled. Triangular grid: 528 tiles
// (si>=ti) per batch, grid (528, 2). Uniform work per block.
// ---------------------------------------------------------------------------
__global__ __launch_bounds__(256, 2)
void score_kernel(const short* __restrict__ Qb, const short* __restrict__ Kb,
                  short* __restrict__ Ab) {
  int idx = blockIdx.x;
  int ti = 0;
  while (idx >= 32 - ti) { idx -= 32 - ti; ++ti; }
  const int si = ti + idx;
  const int b = blockIdx.y;
  const int s0 = si * 128, t0 = ti * 128;

  __shared__ __align__(16) short Qs[128][64];
  __shared__ __align__(16) short Ks[128][64];
  GEMM_DECLS();

  f32x4 acc[4][4];
  ACC_INIT4(acc);

  for (int k0 = 0; k0 < 1024; k0 += 64) {
    __syncthreads();
    STAGE_TILE(Qs, Qb, 1024, b * T_LEN + t0, k0, 128);
    STAGE_TILE(Ks, Kb, 1024, b * T_LEN + s0, k0, 128);
    __syncthreads();
    FRAG_MFMA44(Qs, Ks, acc);
  }

#pragma unroll
  for (int im = 0; im < 4; ++im) {
#pragma unroll
    for (int in = 0; in < 4; ++in) {
      int s = s0 + wn * 64 + in * 16 + l15;
#pragma unroll
      for (int r = 0; r < 4; ++r) {
        int t = t0 + wm * 64 + im * 16 + quad * 4 + r;
        int d = s - t;
        float v = acc[im][in][r];
        v = (d < 0) ? 0.f : v * exp2f((float)d * LOG2G);
        Ab[((size_t)(b * T_LEN + t)) * T_LEN + swzc(s, t)] = f2bf(v);
      }
    }
  }
}

// ---------------------------------------------------------------------------
// Kernel E: out = A' V (fp32). 64-row t-tiles, balanced pairing (p, 63-p):
// uniform 65 BK64-iters per block. grid (32, 2, 8) = 512 blocks.
// di slowest: A-stream-sharing blocks land on one XCD.
// ---------------------------------------------------------------------------
__global__ __launch_bounds__(256, 2)
void av_kernel(const short* __restrict__ Ab, const short* __restrict__ Vt,
               float* __restrict__ Out) {
  const int p = blockIdx.x, b = blockIdx.y, di = blockIdx.z;
  const int n0 = di * 128;

  __shared__ __align__(16) short As2[64][64];
  __shared__ __align__(16) short Vs[128][64];
  GEMM_DECLS();

#pragma unroll 1
  for (int half = 0; half < 2; ++half) {
    const int ti2 = half ? (63 - p) : p;  // 64-row tile index
    const int t0 = ti2 * 64;

    f32x4 acc[2][4];
#pragma unroll
    for (int i = 0; i < 2; ++i)
#pragma unroll
      for (int j = 0; j < 4; ++j) {
        f32x4 z = {0.f, 0.f, 0.f, 0.f};
        acc[i][j] = z;
      }

    for (int s = t0; s < T_LEN; s += 64) {
      __syncthreads();
      STAGE_TILE(As2, Ab, T_LEN, b * T_LEN + t0, s, 64);
      STAGE_TILE(Vs, Vt, 8192, n0, b * T_LEN + s, 128);
      __syncthreads();
      bf16x8 af[2][2], bfr[4][2];
#pragma unroll
      for (int im = 0; im < 2; ++im)
#pragma unroll
        for (int ks = 0; ks < 2; ++ks)
          af[im][ks] = *(const bf16x8*)&As2[wm * 32 + im * 16 + l15]
                           [((ks * 4 + quad) ^ asw) * 8];
#pragma unroll
      for (int in = 0; in < 4; ++in)
#pragma unroll
        for (int ks = 0; ks < 2; ++ks)
          bfr[in][ks] = *(const bf16x8*)&Vs[wn * 64 + in * 16 + l15]
                            [((ks * 4 + quad) ^ asw) * 8];
#pragma unroll
      for (int ks = 0; ks < 2; ++ks)
#pragma unroll
        for (int im = 0; im < 2; ++im)
#pragma unroll
          for (int in = 0; in < 4; ++in)
            acc[im][in] = MFMA16(af[im][ks], bfr[in][ks], acc[im][in]);
    }

#pragma unroll
    for (int im = 0; im < 2; ++im) {
#pragma unroll
      for (int in = 0; in < 4; ++in) {
        int n = n0 + wn * 64 + in * 16 + l15;
#pragma unroll
        for (int r = 0; r < 4; ++r) {
          int t = t0 + wm * 32 + im * 16 + quad * 4 + r;
          Out[((size_t)(b * T_LEN + t)) * 1024 + n] = acc[im][in][r];
        }
      }
    }
  }
}

// ---------------------------------------------------------------------------
// Kernel F: in-place GroupNorm (32 groups x 32 ch). one block per row.
// ---------------------------------------------------------------------------
__global__ __launch_bounds__(256)
void gn_kernel(float* __restrict__ Out, const float* __restrict__ gw,
               const float* __restrict__ gb) {
  const int row = blockIdx.x;
  const int tid = threadIdx.x;
  const int ch0 = tid * 4;
  float4 v = *(const float4*)&Out[(size_t)row * 1024 + ch0];
  float s = v.x + v.y + v.z + v.w;
  float q = v.x * v.x + v.y * v.y + v.z * v.z + v.w * v.w;
  s += __shfl_xor(s, 1, 64);
  q += __shfl_xor(q, 1, 64);
  s += __shfl_xor(s, 2, 64);
  q += __shfl_xor(q, 2, 64);
  s += __shfl_xor(s, 4, 64);
  q += __shfl_xor(q, 4, 64);
  float mean = s * (1.f / 32.f);
  float var = q * (1.f / 32.f) - mean * mean;
  float rstd = rsqrtf(var + 1e-6f);
  float4 o;
  o.x = (v.x - mean) * rstd * gw[ch0 + 0] + gb[ch0 + 0];
  o.y = (v.y - mean) * rstd * gw[ch0 + 1] + gb[ch0 + 1];
  o.z = (v.z - mean) * rstd * gw[ch0 + 2] + gb[ch0 + 2];
  o.w = (v.w - mean) * rstd * gw[ch0 + 3] + gb[ch0 + 3];
  *(float4*)&Out[(size_t)row * 1024 + ch0] = o;
}

// ---------------------------------------------------------------------------
extern "C" void kernel_launch(void* const* d_in, const int* in_sizes, int n_in,
                              void* d_out, int out_size, void* d_ws,
                              size_t ws_size, hipStream_t stream) {
  const float* X = (const float*)d_in[0];
  const float* Wq = (const float*)d_in[1];
  const float* Wk = (const float*)d_in[2];
  const float* Wv = (const float*)d_in[3];
  const float* gw = (const float*)d_in[4];
  const float* gb = (const float*)d_in[5];
  float* Out = (float*)d_out;

  short* Qb = (short*)d_ws;                        // 16 MB
  short* Kb = Qb + (size_t)8192 * 1024;            // 16 MB
  short* Vt = Kb + (size_t)8192 * 1024;            // 16 MB (transposed)
  short* Ab = Vt + (size_t)8192 * 1024;            // 64 MB
  short* Xb = Ab;                                  // aliases Ab (dead after qkv)
  short* WT = Xb + (size_t)8192 * 1024;            // 6 MB

  convert_x<<<4096, 256, 0, stream>>>(X, Xb);
  transpose_w<<<dim3(16, 16, 3), 256, 0, stream>>>(Wq, Wk, Wv, WT);
  qkv_gemm<<<dim3(64, 24), 256, 0, stream>>>(Xb, WT, Qb, Kb, Vt);
  score_kernel<<<dim3(528, 2), 256, 0, stream>>>(Qb, Kb, Ab);
  av_kernel<<<dim3(32, 2, 8), 256, 0, stream>>>(Ab, Vt, Out);
  gn_kernel<<<8192, 256, 0, stream>>>(Out, gw, gb);
}